// Round 1
// baseline (486.642 us; speedup 1.0000x reference)
//
#include <hip/hip_runtime.h>
#include <math.h>

#define BN_EPS 1e-5f

// ---------------------------------------------------------------------------
// Build padded adjacency buckets: slots[d*64 + c] = src for c-th in-edge of d
// ---------------------------------------------------------------------------
__global__ void build_kernel(const int* __restrict__ ei, int* __restrict__ deg,
                             int* __restrict__ slots, int E) {
    int e = blockIdx.x * 256 + threadIdx.x;
    if (e >= E) return;
    int s = ei[e];       // src row
    int d = ei[E + e];   // dst row
    int c = atomicAdd(&deg[d], 1);
    if (c < 64) slots[(size_t)d * 64 + c] = s;
}

// ---------------------------------------------------------------------------
// h[i] = x[i] + sum_{j in N(i)} x[j]   — one wave (64 lanes = 64 feats) / node
// ---------------------------------------------------------------------------
__global__ void gather_kernel(const float* __restrict__ x, const int* __restrict__ slots,
                              const int* __restrict__ deg, float* __restrict__ h, int n) {
    int gid = blockIdx.x * blockDim.x + threadIdx.x;
    int node = gid >> 6;
    if (node >= n) return;
    int lane = threadIdx.x & 63;
    int d = deg[node];
    d = d > 64 ? 64 : d;
    int myslot = slots[(size_t)node * 64 + lane];   // coalesced 256B
    float acc = x[(size_t)node * 64 + lane];        // self term (GIN eps=0)
    for (int c = 0; c < d; ++c) {
        int s = __shfl(myslot, c, 64);
        acc += x[(size_t)s * 64 + lane];
    }
    h[(size_t)node * 64 + lane] = acc;
}

// ---------------------------------------------------------------------------
// Fused GIN MLP: x_out = relu(bn2(relu(bn1(h@W1 + b1)) @ W2 + b2))
// BN folded into weights at stage time. 16-node tiles, fp32, LDS weights.
// LDS total: 32768+32768+512+256+4352+8704 = 79360 B -> 2 blocks/CU
// ---------------------------------------------------------------------------
__global__ __launch_bounds__(256, 2)
void mlp_kernel(const float* __restrict__ hin,
                const float* __restrict__ W1, const float* __restrict__ b1,
                const float* __restrict__ g1, const float* __restrict__ bt1,
                const float* __restrict__ m1, const float* __restrict__ v1,
                const float* __restrict__ W2, const float* __restrict__ b2,
                const float* __restrict__ gc, const float* __restrict__ bc,
                const float* __restrict__ mc, const float* __restrict__ vc,
                float* __restrict__ xout, int n) {
    __shared__ float W1s[64 * 128];
    __shared__ float W2s[128 * 64];
    __shared__ float bias1[128];
    __shared__ float bias2[64];
    __shared__ float hT[64][17];    // [k][node], transposed h tile
    __shared__ float h2T[128][17];  // [k][node], intermediate

    // scale scratch aliased onto tile LDS (dead until after weight staging)
    float* sc1 = &h2T[0][0];  // 128 floats
    float* sc2 = &hT[0][0];   // 64 floats

    int t = threadIdx.x;
    if (t < 128) {
        float inv = rsqrtf(v1[t] + BN_EPS);
        float s = g1[t] * inv;
        sc1[t] = s;
        bias1[t] = b1[t] * s + bt1[t] - m1[t] * s;
    } else if (t < 192) {
        int j = t - 128;
        float inv = rsqrtf(vc[j] + BN_EPS);
        float s = gc[j] * inv;
        sc2[j] = s;
        bias2[j] = b2[j] * s + bc[j] - mc[j] * s;
    }
    __syncthreads();
    for (int i = t; i < 64 * 128; i += 256) W1s[i] = W1[i] * sc1[i & 127];
    for (int i = t; i < 128 * 64; i += 256) W2s[i] = W2[i] * sc2[i & 63];
    __syncthreads();

    const int jA = (t & 31) * 4;  // stage A: 32 col-groups x 4 cols = 128
    const int nA = (t >> 5) * 2;  // stage A: 8 node-groups x 2 nodes = 16
    const int jB = (t & 15) * 4;  // stage B: 16 col-groups x 4 cols = 64
    const int nB = t >> 4;        // stage B: 16 nodes

    for (int tile = blockIdx.x * 16; tile < n; tile += gridDim.x * 16) {
        {   // load h tile, transpose into LDS
            int node = t >> 4;
            int k0 = (t & 15) * 4;
            int nn = tile + node;
            float4 hv = make_float4(0.f, 0.f, 0.f, 0.f);
            if (nn < n) hv = *(const float4*)&hin[(size_t)nn * 64 + k0];
            hT[k0 + 0][node] = hv.x;
            hT[k0 + 1][node] = hv.y;
            hT[k0 + 2][node] = hv.z;
            hT[k0 + 3][node] = hv.w;
        }
        __syncthreads();
        {   // stage A: h(64) @ W1(64x128), 2 nodes x 4 cols per thread
            float a0x = 0.f, a0y = 0.f, a0z = 0.f, a0w = 0.f;
            float a1x = 0.f, a1y = 0.f, a1z = 0.f, a1w = 0.f;
#pragma unroll 8
            for (int k = 0; k < 64; ++k) {
                float4 wv = *(const float4*)&W1s[k * 128 + jA];
                float h0 = hT[k][nA];
                float h1 = hT[k][nA + 1];
                a0x = fmaf(wv.x, h0, a0x);
                a0y = fmaf(wv.y, h0, a0y);
                a0z = fmaf(wv.z, h0, a0z);
                a0w = fmaf(wv.w, h0, a0w);
                a1x = fmaf(wv.x, h1, a1x);
                a1y = fmaf(wv.y, h1, a1y);
                a1z = fmaf(wv.z, h1, a1z);
                a1w = fmaf(wv.w, h1, a1w);
            }
            float4 bb = *(const float4*)&bias1[jA];
            h2T[jA + 0][nA]     = fmaxf(a0x + bb.x, 0.f);
            h2T[jA + 1][nA]     = fmaxf(a0y + bb.y, 0.f);
            h2T[jA + 2][nA]     = fmaxf(a0z + bb.z, 0.f);
            h2T[jA + 3][nA]     = fmaxf(a0w + bb.w, 0.f);
            h2T[jA + 0][nA + 1] = fmaxf(a1x + bb.x, 0.f);
            h2T[jA + 1][nA + 1] = fmaxf(a1y + bb.y, 0.f);
            h2T[jA + 2][nA + 1] = fmaxf(a1z + bb.z, 0.f);
            h2T[jA + 3][nA + 1] = fmaxf(a1w + bb.w, 0.f);
        }
        __syncthreads();
        {   // stage B: h2(128) @ W2(128x64), 1 node x 4 cols per thread
            float c0 = 0.f, c1 = 0.f, c2 = 0.f, c3 = 0.f;
#pragma unroll 8
            for (int k = 0; k < 128; ++k) {
                float4 wv = *(const float4*)&W2s[k * 64 + jB];
                float hv = h2T[k][nB];
                c0 = fmaf(wv.x, hv, c0);
                c1 = fmaf(wv.y, hv, c1);
                c2 = fmaf(wv.z, hv, c2);
                c3 = fmaf(wv.w, hv, c3);
            }
            float4 bb = *(const float4*)&bias2[jB];
            int nn = tile + nB;
            if (nn < n) {
                float4 o;
                o.x = fmaxf(c0 + bb.x, 0.f);
                o.y = fmaxf(c1 + bb.y, 0.f);
                o.z = fmaxf(c2 + bb.z, 0.f);
                o.w = fmaxf(c3 + bb.w, 0.f);
                *(float4*)&xout[(size_t)nn * 64 + jB] = o;
            }
        }
        __syncthreads();
    }
}

// ---------------------------------------------------------------------------
// Head: relu(bn1(x@lin1+b)) @ lin2 + b2 -> log_softmax(40)
// lin2 zero-padded to 64 cols; width-16 shfl_xor reductions for softmax.
// ---------------------------------------------------------------------------
__global__ __launch_bounds__(256, 3)
void head_kernel(const float* __restrict__ xin,
                 const float* __restrict__ l1W, const float* __restrict__ l1b,
                 const float* __restrict__ g, const float* __restrict__ bshift,
                 const float* __restrict__ m, const float* __restrict__ v,
                 const float* __restrict__ l2W, const float* __restrict__ l2b,
                 float* __restrict__ out, int n) {
    __shared__ float W1s[64 * 64];
    __shared__ float W2s[64 * 64];  // cols >= 40 are zero
    __shared__ float bias1[64];
    __shared__ float bias2[64];
    __shared__ float hT[64][17];
    __shared__ float h2T[64][17];
    float* sc1 = &h2T[0][0];

    int t = threadIdx.x;
    if (t < 64) {
        float inv = rsqrtf(v[t] + BN_EPS);
        float s = g[t] * inv;
        sc1[t] = s;
        bias1[t] = l1b[t] * s + bshift[t] - m[t] * s;
        bias2[t] = (t < 40) ? l2b[t] : 0.0f;
    }
    __syncthreads();
    for (int i = t; i < 64 * 64; i += 256) W1s[i] = l1W[i] * sc1[i & 63];
    for (int i = t; i < 64 * 64; i += 256) {
        int j = i & 63, k = i >> 6;
        W2s[i] = (j < 40) ? l2W[k * 40 + j] : 0.0f;
    }
    __syncthreads();

    const int jgrp = t & 15;
    const int j0 = jgrp * 4;
    const int node = t >> 4;

    for (int tile = blockIdx.x * 16; tile < n; tile += gridDim.x * 16) {
        {
            int nn = tile + node;
            float4 hv = make_float4(0.f, 0.f, 0.f, 0.f);
            if (nn < n) hv = *(const float4*)&xin[(size_t)nn * 64 + j0];
            hT[j0 + 0][node] = hv.x;
            hT[j0 + 1][node] = hv.y;
            hT[j0 + 2][node] = hv.z;
            hT[j0 + 3][node] = hv.w;
        }
        __syncthreads();
        float a0 = 0.f, a1 = 0.f, a2 = 0.f, a3 = 0.f;
#pragma unroll 8
        for (int k = 0; k < 64; ++k) {
            float4 wv = *(const float4*)&W1s[k * 64 + j0];
            float hv = hT[k][node];
            a0 = fmaf(wv.x, hv, a0);
            a1 = fmaf(wv.y, hv, a1);
            a2 = fmaf(wv.z, hv, a2);
            a3 = fmaf(wv.w, hv, a3);
        }
        {
            float4 bb = *(const float4*)&bias1[j0];
            h2T[j0 + 0][node] = fmaxf(a0 + bb.x, 0.f);
            h2T[j0 + 1][node] = fmaxf(a1 + bb.y, 0.f);
            h2T[j0 + 2][node] = fmaxf(a2 + bb.z, 0.f);
            h2T[j0 + 3][node] = fmaxf(a3 + bb.w, 0.f);
        }
        __syncthreads();
        float c0 = 0.f, c1 = 0.f, c2 = 0.f, c3 = 0.f;
#pragma unroll 8
        for (int k = 0; k < 64; ++k) {
            float4 wv = *(const float4*)&W2s[k * 64 + j0];
            float hv = h2T[k][node];
            c0 = fmaf(wv.x, hv, c0);
            c1 = fmaf(wv.y, hv, c1);
            c2 = fmaf(wv.z, hv, c2);
            c3 = fmaf(wv.w, hv, c3);
        }
        float4 bb = *(const float4*)&bias2[j0];
        float z0 = c0 + bb.x, z1 = c1 + bb.y, z2 = c2 + bb.z, z3 = c3 + bb.w;
        bool act = (jgrp < 10);  // cols 40..63 are padding
        if (!act) { z0 = -INFINITY; z1 = -INFINITY; z2 = -INFINITY; z3 = -INFINITY; }
        float mx = fmaxf(fmaxf(z0, z1), fmaxf(z2, z3));
        for (int msk = 1; msk < 16; msk <<= 1)
            mx = fmaxf(mx, __shfl_xor(mx, msk, 16));
        float se = 0.f;
        if (act) se = __expf(z0 - mx) + __expf(z1 - mx) + __expf(z2 - mx) + __expf(z3 - mx);
        for (int msk = 1; msk < 16; msk <<= 1)
            se += __shfl_xor(se, msk, 16);
        float lse = mx + __logf(se);
        int nn = tile + node;
        if (act && nn < n) {
            float4 o = make_float4(z0 - lse, z1 - lse, z2 - lse, z3 - lse);
            *(float4*)&out[(size_t)nn * 40 + j0] = o;
        }
        __syncthreads();
    }
}

// ---------------------------------------------------------------------------
extern "C" void kernel_launch(void* const* d_in, const int* in_sizes, int n_in,
                              void* d_out, int out_size, void* d_ws, size_t ws_size,
                              hipStream_t stream) {
    const float* x    = (const float*)d_in[0];
    const int*   ei   = (const int*)d_in[1];
    const float* W1   = (const float*)d_in[2];
    const float* b1   = (const float*)d_in[3];
    const float* g1   = (const float*)d_in[4];
    const float* bt1  = (const float*)d_in[5];
    const float* m1   = (const float*)d_in[6];
    const float* v1   = (const float*)d_in[7];
    const float* W2   = (const float*)d_in[8];
    const float* b2   = (const float*)d_in[9];
    const float* gc   = (const float*)d_in[10];
    const float* bc   = (const float*)d_in[11];
    const float* mc   = (const float*)d_in[12];
    const float* vc   = (const float*)d_in[13];
    const float* l1W  = (const float*)d_in[14];
    const float* l1b  = (const float*)d_in[15];
    const float* gbn  = (const float*)d_in[16];
    const float* bbn  = (const float*)d_in[17];
    const float* mbn  = (const float*)d_in[18];
    const float* vbn  = (const float*)d_in[19];
    const float* l2W  = (const float*)d_in[20];
    const float* l2b  = (const float*)d_in[21];
    float* out = (float*)d_out;

    int N = in_sizes[0] / 64;
    int E = in_sizes[1] / 2;

    char* w = (char*)d_ws;
    int* deg = (int*)w;            w += ((size_t)N * 4 + 255) / 256 * 256;
    int* slots = (int*)w;          w += (size_t)N * 64 * 4;
    float* hbuf = (float*)w;       w += (size_t)N * 64 * 4;
    float* xb0 = (float*)w;        w += (size_t)N * 64 * 4;
    float* xb1 = (float*)w;

    hipMemsetAsync(deg, 0, (size_t)N * 4, stream);
    build_kernel<<<(E + 255) / 256, 256, 0, stream>>>(ei, deg, slots, E);

    const float* cur = x;
    float* nxt[3] = {xb0, xb1, xb0};
    for (int l = 0; l < 3; ++l) {
        gather_kernel<<<(N * 64 + 255) / 256, 256, 0, stream>>>(cur, slots, deg, hbuf, N);
        mlp_kernel<<<512, 256, 0, stream>>>(
            hbuf,
            W1 + (size_t)l * 64 * 128, b1 + (size_t)l * 128, g1 + (size_t)l * 128,
            bt1 + (size_t)l * 128, m1 + (size_t)l * 128, v1 + (size_t)l * 128,
            W2 + (size_t)l * 128 * 64, b2 + (size_t)l * 64, gc + (size_t)l * 64,
            bc + (size_t)l * 64, mc + (size_t)l * 64, vc + (size_t)l * 64,
            nxt[l], N);
        cur = nxt[l];
    }
    head_kernel<<<512, 256, 0, stream>>>(cur, l1W, l1b, gbn, bbn, mbn, vbn, l2W, l2b, out, N);
}

// Round 2
// 358.570 us; speedup vs baseline: 1.3572x; 1.3572x over previous
//
#include <hip/hip_runtime.h>
#include <math.h>

#define BN_EPS 1e-5f

typedef short short8 __attribute__((ext_vector_type(8)));
typedef float floatx4 __attribute__((ext_vector_type(4)));

#define MFMA16(a, b, c) __builtin_amdgcn_mfma_f32_16x16x32_bf16((a), (b), (c), 0, 0, 0)

// fp32 -> bf16 bits, round-to-nearest-even
__device__ __forceinline__ unsigned short f2bf(float x) {
    unsigned u = __float_as_uint(x);
    u = u + 0x7fffu + ((u >> 16) & 1u);
    return (unsigned short)(u >> 16);
}
__device__ __forceinline__ float bf2f(unsigned short b) {
    return __uint_as_float(((unsigned)b) << 16);
}

// ---------------------------------------------------------------------------
// Build padded adjacency buckets: slots[d*64 + c] = src for c-th in-edge of d
// ---------------------------------------------------------------------------
__global__ void build_kernel(const int* __restrict__ ei, int* __restrict__ deg,
                             int* __restrict__ slots, int E) {
    int e = blockIdx.x * 256 + threadIdx.x;
    if (e >= E) return;
    int s = ei[e];       // src row
    int d = ei[E + e];   // dst row
    int c = atomicAdd(&deg[d], 1);
    if (c < 64) slots[(size_t)d * 64 + c] = s;
}

// ---------------------------------------------------------------------------
// Pack BN-folded weights into MFMA B-fragment order, split bf16 hi/lo.
// w1p idx = ((ct*2+kk)*2+hl)*512 + lane*8 + j   (ct<8, kk<2)
// w2p idx = ((ct*4+kk)*2+hl)*512 + lane*8 + j   (ct<4, kk<4)
// frag value: B[k = kk*32 + (lane>>4)*8 + j][n = ct*16 + (lane&15)]
// ---------------------------------------------------------------------------
__global__ void pack_kernel(const float* __restrict__ W1, const float* __restrict__ b1,
                            const float* __restrict__ g1, const float* __restrict__ bt1,
                            const float* __restrict__ m1, const float* __restrict__ v1,
                            const float* __restrict__ W2, const float* __restrict__ b2,
                            const float* __restrict__ gc, const float* __restrict__ bc,
                            const float* __restrict__ mc, const float* __restrict__ vc,
                            unsigned short* __restrict__ w1p, unsigned short* __restrict__ w2p,
                            float* __restrict__ bias1, float* __restrict__ bias2) {
    int l = blockIdx.x, t = threadIdx.x;
    const float* W1l = W1 + (size_t)l * 64 * 128;
    const float* W2l = W2 + (size_t)l * 128 * 64;
    if (t < 128) {
        float s = g1[l * 128 + t] * rsqrtf(v1[l * 128 + t] + BN_EPS);
        bias1[l * 128 + t] = (b1[l * 128 + t] - m1[l * 128 + t]) * s + bt1[l * 128 + t];
    }
    if (t < 64) {
        float s = gc[l * 64 + t] * rsqrtf(vc[l * 64 + t] + BN_EPS);
        bias2[l * 64 + t] = (b2[l * 64 + t] - mc[l * 64 + t]) * s + bc[l * 64 + t];
    }
    for (int idx = t; idx < 16384; idx += 256) {
        int j = idx & 7, lane = (idx >> 3) & 63, hl = (idx >> 9) & 1;
        int kk = (idx >> 10) & 1, ct = idx >> 11;
        int k = kk * 32 + (lane >> 4) * 8 + j;
        int nn = ct * 16 + (lane & 15);
        float s = g1[l * 128 + nn] * rsqrtf(v1[l * 128 + nn] + BN_EPS);
        float w = W1l[k * 128 + nn] * s;
        unsigned short hi = f2bf(w);
        w1p[(size_t)l * 16384 + idx] = hl ? f2bf(w - bf2f(hi)) : hi;
    }
    for (int idx = t; idx < 16384; idx += 256) {
        int j = idx & 7, lane = (idx >> 3) & 63, hl = (idx >> 9) & 1;
        int kk = (idx >> 10) & 3, ct = idx >> 12;
        int k = kk * 32 + (lane >> 4) * 8 + j;
        int nn = ct * 16 + (lane & 15);
        float s = gc[l * 64 + nn] * rsqrtf(vc[l * 64 + nn] + BN_EPS);
        float w = W2l[k * 64 + nn] * s;
        unsigned short hi = f2bf(w);
        w2p[(size_t)l * 16384 + idx] = hl ? f2bf(w - bf2f(hi)) : hi;
    }
}

// ---------------------------------------------------------------------------
// h[i] = x[i] + sum_{j in N(i)} x[j]; one wave per node; 4 load chains for
// latency hiding; emits bf16 hi/lo split for the MFMA MLP A-operand.
// ---------------------------------------------------------------------------
__global__ void gather_kernel(const float* __restrict__ x, const int* __restrict__ slots,
                              const int* __restrict__ deg,
                              unsigned short* __restrict__ hhi,
                              unsigned short* __restrict__ hlo, int n) {
    int gid = blockIdx.x * blockDim.x + threadIdx.x;
    int node = gid >> 6;
    if (node >= n) return;
    int lane = threadIdx.x & 63;
    int d = deg[node];
    d = d > 64 ? 64 : d;
    int myslot = slots[(size_t)node * 64 + lane];   // coalesced 256B
    float acc = x[(size_t)node * 64 + lane];        // self term (GIN eps=0)
    float a1 = 0.f, a2 = 0.f, a3 = 0.f;
    int c = 0;
    for (; c + 4 <= d; c += 4) {
        int s0 = __shfl(myslot, c, 64);
        int s1 = __shfl(myslot, c + 1, 64);
        int s2 = __shfl(myslot, c + 2, 64);
        int s3 = __shfl(myslot, c + 3, 64);
        acc += x[(size_t)s0 * 64 + lane];
        a1  += x[(size_t)s1 * 64 + lane];
        a2  += x[(size_t)s2 * 64 + lane];
        a3  += x[(size_t)s3 * 64 + lane];
    }
    for (; c < d; ++c) {
        int s = __shfl(myslot, c, 64);
        acc += x[(size_t)s * 64 + lane];
    }
    acc += (a1 + a2) + a3;
    unsigned short hi = f2bf(acc);
    unsigned short lo = f2bf(acc - bf2f(hi));
    hhi[(size_t)node * 64 + lane] = hi;
    hlo[(size_t)node * 64 + lane] = lo;
}

// ---------------------------------------------------------------------------
// MFMA GIN MLP, split-bf16 (hi+lo, 3 products) == fp32-accurate.
// Block = 4 waves, one 16-node tile. Wave w owns stage-A col-tiles {2w,2w+1}
// and stage-B col-tile w. Weights live in registers (pre-packed frags).
// LDS: h2 hi/lo [16][136] bf16 (stride 136 -> 2-way = free).
// ---------------------------------------------------------------------------
__global__ __launch_bounds__(256)
void mlp_mfma(const unsigned short* __restrict__ hhi, const unsigned short* __restrict__ hlo,
              const unsigned short* __restrict__ w1p, const unsigned short* __restrict__ w2p,
              const float* __restrict__ bias1, const float* __restrict__ bias2,
              float* __restrict__ xout, int n) {
    __shared__ __attribute__((aligned(16))) unsigned short h2hi[16 * 136];
    __shared__ __attribute__((aligned(16))) unsigned short h2lo[16 * 136];

    const int t = threadIdx.x;
    const int wv = t >> 6, lane = t & 63;
    const int quad = lane >> 4, l16 = lane & 15;

    // ---- preload weight fragments (same for every block; L2-hot) ----
    short8 w1f[2][2][2];   // [ct_local][kk][hi/lo]
#pragma unroll
    for (int c = 0; c < 2; ++c)
#pragma unroll
        for (int kk = 0; kk < 2; ++kk)
#pragma unroll
            for (int hl = 0; hl < 2; ++hl) {
                int ct = wv * 2 + c;
                w1f[c][kk][hl] = *(const short8*)&w1p[(size_t)(((ct * 2 + kk) * 2 + hl) * 64 + lane) * 8];
            }
    short8 w2f[4][2];      // [kk][hi/lo], ct = wv
#pragma unroll
    for (int kk = 0; kk < 4; ++kk)
#pragma unroll
        for (int hl = 0; hl < 2; ++hl)
            w2f[kk][hl] = *(const short8*)&w2p[(size_t)(((wv * 4 + kk) * 2 + hl) * 64 + lane) * 8];

    float b1v0 = bias1[(wv * 2 + 0) * 16 + l16];
    float b1v1 = bias1[(wv * 2 + 1) * 16 + l16];
    float b2v  = bias2[wv * 16 + l16];

    const int tile = blockIdx.x * 16;
    int arow = tile + l16;
    if (arow >= n) arow = n - 1;  // clamp (n % 16 == 0 normally)

    // ---- stage A: h(16x64) @ W1(64x128) ----
    const unsigned short* hr = hhi + (size_t)arow * 64 + quad * 8;
    const unsigned short* lr = hlo + (size_t)arow * 64 + quad * 8;
    short8 ah0 = *(const short8*)hr;
    short8 ah1 = *(const short8*)(hr + 32);
    short8 al0 = *(const short8*)lr;
    short8 al1 = *(const short8*)(lr + 32);

    floatx4 accA0 = {0.f, 0.f, 0.f, 0.f};
    floatx4 accA1 = {0.f, 0.f, 0.f, 0.f};
    accA0 = MFMA16(ah0, w1f[0][0][0], accA0);
    accA0 = MFMA16(ah0, w1f[0][0][1], accA0);
    accA0 = MFMA16(al0, w1f[0][0][0], accA0);
    accA0 = MFMA16(ah1, w1f[0][1][0], accA0);
    accA0 = MFMA16(ah1, w1f[0][1][1], accA0);
    accA0 = MFMA16(al1, w1f[0][1][0], accA0);
    accA1 = MFMA16(ah0, w1f[1][0][0], accA1);
    accA1 = MFMA16(ah0, w1f[1][0][1], accA1);
    accA1 = MFMA16(al0, w1f[1][0][0], accA1);
    accA1 = MFMA16(ah1, w1f[1][1][0], accA1);
    accA1 = MFMA16(ah1, w1f[1][1][1], accA1);
    accA1 = MFMA16(al1, w1f[1][1][0], accA1);

    // epilogue A: bias+relu, split hi/lo, write LDS (D: row=quad*4+r, col=lane&15)
#pragma unroll
    for (int r = 0; r < 4; ++r) {
        int node = quad * 4 + r;
        {
            float v = fmaxf(accA0[r] + b1v0, 0.f);
            unsigned short hi = f2bf(v);
            int col = (wv * 2 + 0) * 16 + l16;
            h2hi[node * 136 + col] = hi;
            h2lo[node * 136 + col] = f2bf(v - bf2f(hi));
        }
        {
            float v = fmaxf(accA1[r] + b1v1, 0.f);
            unsigned short hi = f2bf(v);
            int col = (wv * 2 + 1) * 16 + l16;
            h2hi[node * 136 + col] = hi;
            h2lo[node * 136 + col] = f2bf(v - bf2f(hi));
        }
    }
    __syncthreads();

    // ---- stage B: h2(16x128) @ W2(128x64) ----
    floatx4 accB = {0.f, 0.f, 0.f, 0.f};
#pragma unroll
    for (int kk = 0; kk < 4; ++kk) {
        short8 a2h = *(const short8*)&h2hi[l16 * 136 + kk * 32 + quad * 8];
        short8 a2l = *(const short8*)&h2lo[l16 * 136 + kk * 32 + quad * 8];
        accB = MFMA16(a2h, w2f[kk][0], accB);
        accB = MFMA16(a2h, w2f[kk][1], accB);
        accB = MFMA16(a2l, w2f[kk][0], accB);
    }
    int col2 = wv * 16 + l16;
#pragma unroll
    for (int r = 0; r < 4; ++r) {
        int node = tile + quad * 4 + r;
        if (node < n)
            xout[(size_t)node * 64 + col2] = fmaxf(accB[r] + b2v, 0.f);
    }
}

// ---------------------------------------------------------------------------
// Head: relu(bn1(x@lin1+b)) @ lin2 + b2 -> log_softmax(40)  (fp32 VALU)
// ---------------------------------------------------------------------------
__global__ __launch_bounds__(256, 3)
void head_kernel(const float* __restrict__ xin,
                 const float* __restrict__ l1W, const float* __restrict__ l1b,
                 const float* __restrict__ g, const float* __restrict__ bshift,
                 const float* __restrict__ m, const float* __restrict__ v,
                 const float* __restrict__ l2W, const float* __restrict__ l2b,
                 float* __restrict__ out, int n) {
    __shared__ float W1s[64 * 64];
    __shared__ float W2s[64 * 64];  // cols >= 40 are zero
    __shared__ float bias1[64];
    __shared__ float bias2[64];
    __shared__ float hT[64][17];
    __shared__ float h2T[64][17];
    float* sc1 = &h2T[0][0];

    int t = threadIdx.x;
    if (t < 64) {
        float inv = rsqrtf(v[t] + BN_EPS);
        float s = g[t] * inv;
        sc1[t] = s;
        bias1[t] = l1b[t] * s + bshift[t] - m[t] * s;
        bias2[t] = (t < 40) ? l2b[t] : 0.0f;
    }
    __syncthreads();
    for (int i = t; i < 64 * 64; i += 256) W1s[i] = l1W[i] * sc1[i & 63];
    for (int i = t; i < 64 * 64; i += 256) {
        int j = i & 63, k = i >> 6;
        W2s[i] = (j < 40) ? l2W[k * 40 + j] : 0.0f;
    }
    __syncthreads();

    const int jgrp = t & 15;
    const int j0 = jgrp * 4;
    const int node = t >> 4;

    for (int tile = blockIdx.x * 16; tile < n; tile += gridDim.x * 16) {
        {
            int nn = tile + node;
            float4 hv = make_float4(0.f, 0.f, 0.f, 0.f);
            if (nn < n) hv = *(const float4*)&xin[(size_t)nn * 64 + j0];
            hT[j0 + 0][node] = hv.x;
            hT[j0 + 1][node] = hv.y;
            hT[j0 + 2][node] = hv.z;
            hT[j0 + 3][node] = hv.w;
        }
        __syncthreads();
        float a0 = 0.f, a1 = 0.f, a2 = 0.f, a3 = 0.f;
#pragma unroll 8
        for (int k = 0; k < 64; ++k) {
            float4 wv = *(const float4*)&W1s[k * 64 + j0];
            float hv = hT[k][node];
            a0 = fmaf(wv.x, hv, a0);
            a1 = fmaf(wv.y, hv, a1);
            a2 = fmaf(wv.z, hv, a2);
            a3 = fmaf(wv.w, hv, a3);
        }
        {
            float4 bb = *(const float4*)&bias1[j0];
            h2T[j0 + 0][node] = fmaxf(a0 + bb.x, 0.f);
            h2T[j0 + 1][node] = fmaxf(a1 + bb.y, 0.f);
            h2T[j0 + 2][node] = fmaxf(a2 + bb.z, 0.f);
            h2T[j0 + 3][node] = fmaxf(a3 + bb.w, 0.f);
        }
        __syncthreads();
        float c0 = 0.f, c1 = 0.f, c2 = 0.f, c3 = 0.f;
#pragma unroll 8
        for (int k = 0; k < 64; ++k) {
            float4 wv = *(const float4*)&W2s[k * 64 + j0];
            float hv = h2T[k][node];
            c0 = fmaf(wv.x, hv, c0);
            c1 = fmaf(wv.y, hv, c1);
            c2 = fmaf(wv.z, hv, c2);
            c3 = fmaf(wv.w, hv, c3);
        }
        float4 bb = *(const float4*)&bias2[j0];
        float z0 = c0 + bb.x, z1 = c1 + bb.y, z2 = c2 + bb.z, z3 = c3 + bb.w;
        bool act = (jgrp < 10);  // cols 40..63 are padding
        if (!act) { z0 = -INFINITY; z1 = -INFINITY; z2 = -INFINITY; z3 = -INFINITY; }
        float mx = fmaxf(fmaxf(z0, z1), fmaxf(z2, z3));
        for (int msk = 1; msk < 16; msk <<= 1)
            mx = fmaxf(mx, __shfl_xor(mx, msk, 16));
        float se = 0.f;
        if (act) se = __expf(z0 - mx) + __expf(z1 - mx) + __expf(z2 - mx) + __expf(z3 - mx);
        for (int msk = 1; msk < 16; msk <<= 1)
            se += __shfl_xor(se, msk, 16);
        float lse = mx + __logf(se);
        int nn = tile + node;
        if (act && nn < n) {
            float4 o = make_float4(z0 - lse, z1 - lse, z2 - lse, z3 - lse);
            *(float4*)&out[(size_t)nn * 40 + j0] = o;
        }
        __syncthreads();
    }
}

// ---------------------------------------------------------------------------
extern "C" void kernel_launch(void* const* d_in, const int* in_sizes, int n_in,
                              void* d_out, int out_size, void* d_ws, size_t ws_size,
                              hipStream_t stream) {
    const float* x    = (const float*)d_in[0];
    const int*   ei   = (const int*)d_in[1];
    const float* W1   = (const float*)d_in[2];
    const float* b1   = (const float*)d_in[3];
    const float* g1   = (const float*)d_in[4];
    const float* bt1  = (const float*)d_in[5];
    const float* m1   = (const float*)d_in[6];
    const float* v1   = (const float*)d_in[7];
    const float* W2   = (const float*)d_in[8];
    const float* b2   = (const float*)d_in[9];
    const float* gc   = (const float*)d_in[10];
    const float* bc   = (const float*)d_in[11];
    const float* mc   = (const float*)d_in[12];
    const float* vc   = (const float*)d_in[13];
    const float* l1W  = (const float*)d_in[14];
    const float* l1b  = (const float*)d_in[15];
    const float* gbn  = (const float*)d_in[16];
    const float* bbn  = (const float*)d_in[17];
    const float* mbn  = (const float*)d_in[18];
    const float* vbn  = (const float*)d_in[19];
    const float* l2W  = (const float*)d_in[20];
    const float* l2b  = (const float*)d_in[21];
    float* out = (float*)d_out;

    int N = in_sizes[0] / 64;
    int E = in_sizes[1] / 2;

    char* w = (char*)d_ws;
    int* deg = (int*)w;              w += ((size_t)N * 4 + 255) / 256 * 256;
    int* slots = (int*)w;            w += (size_t)N * 64 * 4;
    unsigned short* hhi = (unsigned short*)w;  w += (size_t)N * 64 * 2;
    unsigned short* hlo = (unsigned short*)w;  w += (size_t)N * 64 * 2;
    float* xb0 = (float*)w;          w += (size_t)N * 64 * 4;
    unsigned short* w1p = (unsigned short*)w;  w += 3 * 16384 * 2;
    unsigned short* w2p = (unsigned short*)w;  w += 3 * 16384 * 2;
    float* bias1 = (float*)w;        w += 3 * 128 * 4;
    float* bias2 = (float*)w;        w += 3 * 64 * 4;

    hipMemsetAsync(deg, 0, (size_t)N * 4, stream);
    build_kernel<<<(E + 255) / 256, 256, 0, stream>>>(ei, deg, slots, E);
    pack_kernel<<<3, 256, 0, stream>>>(W1, b1, g1, bt1, m1, v1, W2, b2, gc, bc, mc, vc,
                                       w1p, w2p, bias1, bias2);

    const float* cur = x;
    int nblk = (N + 15) / 16;
    for (int l = 0; l < 3; ++l) {
        gather_kernel<<<(N * 64 + 255) / 256, 256, 0, stream>>>(cur, slots, deg, hhi, hlo, N);
        mlp_mfma<<<nblk, 256, 0, stream>>>(hhi, hlo,
                                           w1p + (size_t)l * 16384, w2p + (size_t)l * 16384,
                                           bias1 + (size_t)l * 128, bias2 + (size_t)l * 64,
                                           xb0, N);
        cur = xb0;
    }
    head_kernel<<<512, 256, 0, stream>>>(xb0, l1W, l1b, gbn, bbn, mbn, vbn, l2W, l2b, out, N);
}